// Round 4
// baseline (40.201 us; speedup 1.0000x reference)
//
#include <hip/hip_runtime.h>
#include <hip/hip_bf16.h>

#define BS 32
#define NQ 300
#define NC 92
#define NT 50
#define Q_TOT (BS * NQ)     // 9600
#define T_TOT (BS * NT)     // 1600
#define T4    (T_TOT / 4)   // 400 float4 chunks per output row
#define SLOTS (Q_TOT * T4)  // 3,840,000 float4 slots
#define K2_BLOCK 256
#define K2_GRID (SLOTS / K2_BLOCK)  // 15000, exact

// K1: full softmax prob matrix [Q_TOT, NC] into d_ws. One wave per row.
__global__ __launch_bounds__(256) void probs_kernel(
    const float* __restrict__ logits,   // [Q_TOT, NC]
    float* __restrict__ probs)          // [Q_TOT, NC]
{
    const int row  = blockIdx.x * 4 + (threadIdx.x >> 6);
    const int lane = threadIdx.x & 63;

    const float* rp = logits + (size_t)row * NC;
    float x0 = (lane < NC)      ? rp[lane]      : -INFINITY;
    float x1 = (lane + 64 < NC) ? rp[lane + 64] : -INFINITY;

    float m = fmaxf(x0, x1);
    #pragma unroll
    for (int off = 1; off < 64; off <<= 1)
        m = fmaxf(m, __shfl_xor(m, off));

    const float e0 = __expf(x0 - m);    // exp(-inf - m) == 0 for pad lanes
    const float e1 = __expf(x1 - m);
    float s = e0 + e1;
    #pragma unroll
    for (int off = 1; off < 64; off <<= 1)
        s += __shfl_xor(s, off);

    const float inv = 1.0f / s;
    float* wp = probs + (size_t)row * NC;
    if (lane < NC)      wp[lane]      = e0 * inv;
    if (lane + 64 < NC) wp[lane + 64] = e1 * inv;
}

// One output element's cost. q-side xyxy precomputed by caller.
__device__ __forceinline__ float elem_cost(
    float4 qb, float qx0, float qy0, float qx1, float qy1, float qarea,
    float4 tb, float prob)
{
    // L1 in cxcywh space
    const float l1 = fabsf(qb.x - tb.x) + fabsf(qb.y - tb.y)
                   + fabsf(qb.z - tb.z) + fabsf(qb.w - tb.w);

    const float tx0 = tb.x - 0.5f * tb.z, ty0 = tb.y - 0.5f * tb.w;
    const float tx1 = tb.x + 0.5f * tb.z, ty1 = tb.y + 0.5f * tb.w;
    const float tarea = tb.z * tb.w;

    const float ix0 = fmaxf(qx0, tx0), iy0 = fmaxf(qy0, ty0);
    const float ix1 = fminf(qx1, tx1), iy1 = fminf(qy1, ty1);
    const float iw = fmaxf(ix1 - ix0, 0.0f), ih = fmaxf(iy1 - iy0, 0.0f);
    const float inter = iw * ih;
    const float uni   = qarea + tarea - inter;

    // enclosing box covers both boxes; w/h > 0 by construction
    const float ex0 = fminf(qx0, tx0), ey0 = fminf(qy0, ty0);
    const float ex1 = fmaxf(qx1, tx1), ey1 = fmaxf(qy1, ty1);
    const float earea = (ex1 - ex0) * (ey1 - ey0);

    // giou = inter/uni - (earea-uni)/earea = (inter*earea - ue + uni^2)*rcp(ue)
    const float ue = uni * earea;
    const float r  = __builtin_amdgcn_rcpf(ue);
    float num = inter * earea - ue;
    num = fmaf(uni, uni, num);
    const float giou = num * r;

    return l1 - prob - giou;
}

// K2: one thread = one float4 output slot (q, t0..t0+3). No per-thread loop.
__global__ __launch_bounds__(K2_BLOCK, 6) void cost4_kernel(
    const float* __restrict__ probs,        // [Q_TOT, NC] (d_ws)
    const float* __restrict__ pred_boxes,   // [Q_TOT, 4] cxcywh
    const int*   __restrict__ tgt_labels,   // [T_TOT]
    const float* __restrict__ tgt_boxes,    // [T_TOT, 4] cxcywh
    float* __restrict__ out)                // [Q_TOT, T_TOT]
{
    const int slot = blockIdx.x * K2_BLOCK + threadIdx.x;
    const int q  = slot / T4;               // constant divisor -> magic mul
    const int r  = slot - q * T4;
    const int t0 = r * 4;

    // q-side (shared by 400 consecutive threads -> L1 broadcast)
    const float4 qb = *reinterpret_cast<const float4*>(pred_boxes + 4 * q);
    const float qx0 = qb.x - 0.5f * qb.z, qy0 = qb.y - 0.5f * qb.w;
    const float qx1 = qb.x + 0.5f * qb.z, qy1 = qb.y + 0.5f * qb.w;
    const float qarea = qb.z * qb.w;

    // t-side: 64B contiguous per thread, coalesced across the wave
    const float4* tbp = reinterpret_cast<const float4*>(tgt_boxes + 4 * t0);
    const float4 tb0 = tbp[0], tb1 = tbp[1], tb2 = tbp[2], tb3 = tbp[3];
    const int4 lbl = *reinterpret_cast<const int4*>(tgt_labels + t0);

    const float* pq = probs + (size_t)q * NC;
    const float p0 = pq[lbl.x], p1 = pq[lbl.y], p2 = pq[lbl.z], p3 = pq[lbl.w];

    float4 res;
    res.x = elem_cost(qb, qx0, qy0, qx1, qy1, qarea, tb0, p0);
    res.y = elem_cost(qb, qx0, qy0, qx1, qy1, qarea, tb1, p1);
    res.z = elem_cost(qb, qx0, qy0, qx1, qy1, qarea, tb2, p2);
    res.w = elem_cost(qb, qx0, qy0, qx1, qy1, qarea, tb3, p3);

    *reinterpret_cast<float4*>(out + (size_t)q * T_TOT + t0) = res;
}

extern "C" void kernel_launch(void* const* d_in, const int* in_sizes, int n_in,
                              void* d_out, int out_size, void* d_ws, size_t ws_size,
                              hipStream_t stream) {
    const float* pred_logits = (const float*)d_in[0]; // [32,300,92]
    const float* pred_boxes  = (const float*)d_in[1]; // [32,300,4]
    const int*   tgt_labels  = (const int*)d_in[2];   // [32,50]
    const float* tgt_boxes   = (const float*)d_in[3]; // [32,50,4]
    float* out   = (float*)d_out;                     // [32,300,1600]
    float* probs = (float*)d_ws;                      // [9600,92] = 3.53 MB

    probs_kernel<<<Q_TOT / 4, 256, 0, stream>>>(pred_logits, probs);
    cost4_kernel<<<K2_GRID, K2_BLOCK, 0, stream>>>(probs, pred_boxes,
                                                   tgt_labels, tgt_boxes, out);
}

// Round 5
// 32.934 us; speedup vs baseline: 1.2207x; 1.2207x over previous
//
#include <hip/hip_runtime.h>
#include <hip/hip_bf16.h>

#define BS 32
#define NQ 300
#define NC 92
#define NT 50
#define Q_TOT (BS * NQ)     // 9600
#define T_TOT (BS * NT)     // 1600

#define TILE_Q 64           // q rows per block
#define TILE_T 64           // t cols per block
#define BLK    256          // 16 tx (t-quads) x 16 ty (q-quads)

// K1: full softmax prob matrix [Q_TOT, NC] into d_ws. One wave per row.
__global__ __launch_bounds__(256) void probs_kernel(
    const float* __restrict__ logits,   // [Q_TOT, NC]
    float* __restrict__ probs)          // [Q_TOT, NC]
{
    const int row  = blockIdx.x * 4 + (threadIdx.x >> 6);
    const int lane = threadIdx.x & 63;

    const float* rp = logits + (size_t)row * NC;
    float x0 = (lane < NC)      ? rp[lane]      : -INFINITY;
    float x1 = (lane + 64 < NC) ? rp[lane + 64] : -INFINITY;

    float m = fmaxf(x0, x1);
    #pragma unroll
    for (int off = 1; off < 64; off <<= 1)
        m = fmaxf(m, __shfl_xor(m, off));

    const float e0 = __expf(x0 - m);    // exp(-inf - m) == 0 for pad lanes
    const float e1 = __expf(x1 - m);
    float s = e0 + e1;
    #pragma unroll
    for (int off = 1; off < 64; off <<= 1)
        s += __shfl_xor(s, off);

    const float inv = 1.0f / s;
    float* wp = probs + (size_t)row * NC;
    if (lane < NC)      wp[lane]      = e0 * inv;
    if (lane + 64 < NC) wp[lane + 64] = e1 * inv;
}

// K2: 4q x 4t register tile per thread. 16 independent element chains (ILP),
// float4 stores, probs staged cooperatively into LDS (no divergent global
// gathers in the hot path).
__global__ __launch_bounds__(BLK) void cost_tile_kernel(
    const float* __restrict__ probs,        // [Q_TOT, NC] (d_ws)
    const float* __restrict__ pred_boxes,   // [Q_TOT, 4] cxcywh
    const int*   __restrict__ tgt_labels,   // [T_TOT]
    const float* __restrict__ tgt_boxes,    // [T_TOT, 4] cxcywh
    float* __restrict__ out)                // [Q_TOT, T_TOT]
{
    __shared__ float s_probs[TILE_Q * NC];  // 64 rows x 92 = 23.5 KB

    const int tid = threadIdx.x;
    const int tx  = tid & 15;               // t-quad within tile
    const int ty  = tid >> 4;               // q-quad within tile
    const int q0  = blockIdx.y * TILE_Q;
    const int t0  = (blockIdx.x * 16 + tx) * 4;

    // ---- Stage this tile's prob rows into LDS (coalesced) ----
    {
        const float* gp = probs + (size_t)q0 * NC;
        for (int i = tid; i < TILE_Q * NC; i += BLK)
            s_probs[i] = gp[i];
    }

    // ---- t-side: 4 targets in registers ----
    const float4* tbp = reinterpret_cast<const float4*>(tgt_boxes + 4 * t0);
    const float4 tb[4] = {tbp[0], tbp[1], tbp[2], tbp[3]};
    const int4 lbl = *reinterpret_cast<const int4*>(tgt_labels + t0);

    float ttx0[4], tty0[4], ttx1[4], tty1[4], tar[4];
    #pragma unroll
    for (int j = 0; j < 4; ++j) {
        ttx0[j] = tb[j].x - 0.5f * tb[j].z;  tty0[j] = tb[j].y - 0.5f * tb[j].w;
        ttx1[j] = tb[j].x + 0.5f * tb[j].z;  tty1[j] = tb[j].y + 0.5f * tb[j].w;
        tar[j]  = tb[j].z * tb[j].w;
    }

    __syncthreads();

    // ---- 4 q rows, each producing one float4 store ----
    #pragma unroll
    for (int qi = 0; qi < 4; ++qi) {
        const int qr = ty * 4 + qi;          // local q row 0..63
        const int q  = q0 + qr;
        const float4 qb = *reinterpret_cast<const float4*>(pred_boxes + 4 * q);
        const float qx0 = qb.x - 0.5f * qb.z, qy0 = qb.y - 0.5f * qb.w;
        const float qx1 = qb.x + 0.5f * qb.z, qy1 = qb.y + 0.5f * qb.w;
        const float qarea = qb.z * qb.w;

        const float* pr = s_probs + qr * NC;
        const float p[4] = {pr[lbl.x], pr[lbl.y], pr[lbl.z], pr[lbl.w]};

        float4 res;
        float* resp = &res.x;
        #pragma unroll
        for (int j = 0; j < 4; ++j) {
            // L1 in cxcywh space
            const float l1 = fabsf(qb.x - tb[j].x) + fabsf(qb.y - tb[j].y)
                           + fabsf(qb.z - tb[j].z) + fabsf(qb.w - tb[j].w);

            const float ix0 = fmaxf(qx0, ttx0[j]), iy0 = fmaxf(qy0, tty0[j]);
            const float ix1 = fminf(qx1, ttx1[j]), iy1 = fminf(qy1, tty1[j]);
            const float iw = fmaxf(ix1 - ix0, 0.0f), ih = fmaxf(iy1 - iy0, 0.0f);
            const float inter = iw * ih;
            const float uni   = qarea + tar[j] - inter;

            // enclosing box covers both; w/h > 0 by construction
            const float ex0 = fminf(qx0, ttx0[j]), ey0 = fminf(qy0, tty0[j]);
            const float ex1 = fmaxf(qx1, ttx1[j]), ey1 = fmaxf(qy1, tty1[j]);
            const float earea = (ex1 - ex0) * (ey1 - ey0);

            // giou = inter/uni - (earea-uni)/earea = (inter*earea - ue + uni^2)*rcp(ue)
            const float ue = uni * earea;
            const float r  = __builtin_amdgcn_rcpf(ue);
            float num = inter * earea - ue;
            num = fmaf(uni, uni, num);
            const float giou = num * r;

            resp[j] = l1 - p[j] - giou;
        }
        *reinterpret_cast<float4*>(out + (size_t)q * T_TOT + t0) = res;
    }
}

extern "C" void kernel_launch(void* const* d_in, const int* in_sizes, int n_in,
                              void* d_out, int out_size, void* d_ws, size_t ws_size,
                              hipStream_t stream) {
    const float* pred_logits = (const float*)d_in[0]; // [32,300,92]
    const float* pred_boxes  = (const float*)d_in[1]; // [32,300,4]
    const int*   tgt_labels  = (const int*)d_in[2];   // [32,50]
    const float* tgt_boxes   = (const float*)d_in[3]; // [32,50,4]
    float* out   = (float*)d_out;                     // [32,300,1600]
    float* probs = (float*)d_ws;                      // [9600,92] = 3.53 MB

    probs_kernel<<<Q_TOT / 4, 256, 0, stream>>>(pred_logits, probs);

    dim3 grid(T_TOT / TILE_T, Q_TOT / TILE_Q);        // (25, 150)
    cost_tile_kernel<<<grid, BLK, 0, stream>>>(probs, pred_boxes,
                                               tgt_labels, tgt_boxes, out);
}